// Round 2
// baseline (686.503 us; speedup 1.0000x reference)
//
#include <hip/hip_runtime.h>
#include <math.h>
#include <stdint.h>

// Geometry constants
#define VIEWS 512
#define NDET 736
#define NX 256
#define NY 256
#define EXTENT 2
#define SINO_LEN (VIEWS * NDET)          // 376832
#define NVOX (NX * NY)                   // 65536
#define PER_VOX (VIEWS * EXTENT)         // 1024

// SCALE = (2*pi - 0) / (2 * VIEWS * EXTENT) = pi / 1024
__device__ __constant__ float kScale = (float)(M_PI / 1024.0);

typedef int   v4i __attribute__((ext_vector_type(4)));
typedef float v4f __attribute__((ext_vector_type(4)));

// One wave (64 lanes) per voxel. Each lane handles 16 elements.
//
// KEY CHANGE (round 2): the 537 MB/dispatch index+weight stream was
// thrashing the 4 MiB per-XCD L2s, evicting the 1.47 MB x array, so all
// 67.1M random 4B gathers fell through to the Infinity Cache at 64B line
// granularity -> ~13.5 TB/s internal L3 traffic = the measured ceiling.
// The streams are now NON-TEMPORAL (nt cache policy: stream through,
// don't displace resident lines), keeping x L2-resident so the gathers
// are served by L2 (34.5 TB/s aggregate) instead of L3.
__global__ __launch_bounds__(256) void backproj_kernel(
    const float* __restrict__ x,      // [SINO_LEN]
    const float* __restrict__ weight, // [NVOX * PER_VOX]
    const float* __restrict__ bias,   // [NVOX]
    const int*   __restrict__ indices,// [NVOX * PER_VOX]
    float*       __restrict__ out)    // [NVOX]
{
    const int wave_in_block = threadIdx.x >> 6;
    const int lane          = threadIdx.x & 63;
    const int v             = blockIdx.x * 4 + wave_in_block; // voxel id
    const size_t base       = (size_t)v * PER_VOX;

    const v4i* ip = (const v4i*)(indices + base);
    const v4f* wp = (const v4f*)(weight + base);

    // Phase 1: issue all streaming loads up front, NON-TEMPORAL.
    v4i i4[4];
    v4f w4[4];
#pragma unroll
    for (int k = 0; k < 4; ++k)
        i4[k] = __builtin_nontemporal_load(&ip[lane + k * 64]);
#pragma unroll
    for (int k = 0; k < 4; ++k)
        w4[k] = __builtin_nontemporal_load(&wp[lane + k * 64]);

    // Phase 2: issue all 16 gathers (normal cache policy: x lines stay
    // resident in L1/L2).
    float g[16];
#pragma unroll
    for (int k = 0; k < 4; ++k) {
        g[4 * k + 0] = x[i4[k].x];
        g[4 * k + 1] = x[i4[k].y];
        g[4 * k + 2] = x[i4[k].z];
        g[4 * k + 3] = x[i4[k].w];
    }

    // Phase 3: weighted sum.
    float s = 0.0f;
#pragma unroll
    for (int k = 0; k < 4; ++k) {
        s += g[4 * k + 0] * w4[k].x;
        s += g[4 * k + 1] * w4[k].y;
        s += g[4 * k + 2] * w4[k].z;
        s += g[4 * k + 3] * w4[k].w;
    }

    // wave-64 reduction
#pragma unroll
    for (int off = 32; off > 0; off >>= 1)
        s += __shfl_down(s, off, 64);

    if (lane == 0) {
        // flip over both spatial axes: flattened index reversal
        out[NVOX - 1 - v] = bias[v] + kScale * s;
    }
}

extern "C" void kernel_launch(void* const* d_in, const int* in_sizes, int n_in,
                              void* d_out, int out_size, void* d_ws, size_t ws_size,
                              hipStream_t stream) {
    const float* x       = (const float*)d_in[0];
    const float* weight  = (const float*)d_in[1];
    const float* bias    = (const float*)d_in[2];
    const int*   indices = (const int*)d_in[3];
    float*       out     = (float*)d_out;

    // 4 waves per block, 1 voxel per wave
    const int blocks = NVOX / 4; // 16384
    backproj_kernel<<<blocks, 256, 0, stream>>>(x, weight, bias, indices, out);
}

// Round 3
// 683.901 us; speedup vs baseline: 1.0038x; 1.0038x over previous
//
#include <hip/hip_runtime.h>
#include <math.h>
#include <stdint.h>

// Geometry constants
#define VIEWS 512
#define NDET 736
#define NX 256
#define NY 256
#define EXTENT 2
#define SINO_LEN (VIEWS * NDET)          // 376832
#define NVOX (NX * NY)                   // 65536
#define PER_VOX (VIEWS * EXTENT)         // 1024

// SCALE = (2*pi - 0) / (2 * VIEWS * EXTENT) = pi / 1024
__device__ __constant__ float kScale = (float)(M_PI / 1024.0);

typedef int   v4i __attribute__((ext_vector_type(4)));
typedef float v4f __attribute__((ext_vector_type(4)));

// One wave (64 lanes) per voxel; lane handles 16 elements.
//
// Bottleneck model (r0-r2 evidence): 67.1M mandatory random 4B gathers
// are processed at ~11.4 req/cyc/XCD vs ~16 nominal L2 channel rate.
// sc0 L1-bypass: 0%. nt streams: +3.5%. Issue restructure: 0%.
// => request-rate bound; in-flight depth already HW-queue-capped.
//
// This version: nt streams kept; INDEX loads issued first, gathers for
// chunk k issued as soon as i4[k] lands, WEIGHT loads deferred until all
// gathers are in flight (weights are only needed at consumption time).
// Removes 4 stream loads from the vmcnt window that gates gather issue.
__global__ __launch_bounds__(256) void backproj_kernel(
    const float* __restrict__ x,      // [SINO_LEN]
    const float* __restrict__ weight, // [NVOX * PER_VOX]
    const float* __restrict__ bias,   // [NVOX]
    const int*   __restrict__ indices,// [NVOX * PER_VOX]
    float*       __restrict__ out)    // [NVOX]
{
    const int wave_in_block = threadIdx.x >> 6;
    const int lane          = threadIdx.x & 63;
    const int v             = blockIdx.x * 4 + wave_in_block; // voxel id
    const size_t base       = (size_t)v * PER_VOX;

    const v4i* ip = (const v4i*)(indices + base);
    const v4f* wp = (const v4f*)(weight + base);

    // Phase 1: issue all 4 index loads (non-temporal, coalesced 16B/lane).
    v4i i4[4];
#pragma unroll
    for (int k = 0; k < 4; ++k)
        i4[k] = __builtin_nontemporal_load(&ip[lane + k * 64]);

    // Phase 2: issue gathers per chunk as soon as its indices land.
    float g[16];
#pragma unroll
    for (int k = 0; k < 4; ++k) {
        g[4 * k + 0] = x[i4[k].x];
        g[4 * k + 1] = x[i4[k].y];
        g[4 * k + 2] = x[i4[k].z];
        g[4 * k + 3] = x[i4[k].w];
    }

    // Phase 3: weight loads (non-temporal) — they only gate the FMAs,
    // which are the last consumers; their latency hides under the
    // outstanding gathers.
    v4f w4[4];
#pragma unroll
    for (int k = 0; k < 4; ++k)
        w4[k] = __builtin_nontemporal_load(&wp[lane + k * 64]);

    // Phase 4: weighted sum.
    float s = 0.0f;
#pragma unroll
    for (int k = 0; k < 4; ++k) {
        s += g[4 * k + 0] * w4[k].x;
        s += g[4 * k + 1] * w4[k].y;
        s += g[4 * k + 2] * w4[k].z;
        s += g[4 * k + 3] * w4[k].w;
    }

    // wave-64 reduction
#pragma unroll
    for (int off = 32; off > 0; off >>= 1)
        s += __shfl_down(s, off, 64);

    if (lane == 0) {
        // flip over both spatial axes: flattened index reversal
        out[NVOX - 1 - v] = bias[v] + kScale * s;
    }
}

extern "C" void kernel_launch(void* const* d_in, const int* in_sizes, int n_in,
                              void* d_out, int out_size, void* d_ws, size_t ws_size,
                              hipStream_t stream) {
    const float* x       = (const float*)d_in[0];
    const float* weight  = (const float*)d_in[1];
    const float* bias    = (const float*)d_in[2];
    const int*   indices = (const int*)d_in[3];
    float*       out     = (float*)d_out;

    // 4 waves per block, 1 voxel per wave
    const int blocks = NVOX / 4; // 16384
    backproj_kernel<<<blocks, 256, 0, stream>>>(x, weight, bias, indices, out);
}

// Round 4
// 613.058 us; speedup vs baseline: 1.1198x; 1.1156x over previous
//
#include <hip/hip_runtime.h>
#include <hip/hip_fp16.h>
#include <math.h>
#include <stdint.h>

// Geometry constants
#define VIEWS 512
#define NDET 736
#define NX 256
#define NY 256
#define EXTENT 2
#define SINO_LEN (VIEWS * NDET)          // 376832
#define NVOX (NX * NY)                   // 65536
#define PER_VOX (VIEWS * EXTENT)         // 1024

// fp16 x segmentation
#define SEGB 65536                       // bytes of fp16 x staged per pass (64KB LDS)
#define NPASS 12                         // ceil(SINO_LEN*2 / SEGB) = ceil(753664/65536)
#define XWS_BYTES (NPASS * SEGB)         // 786432: staged-readable region in d_ws
#define XWS_HALVES (XWS_BYTES / 2)       // 393216 (zero-padded past 376832)

// SCALE = (2*pi - 0) / (2 * VIEWS * EXTENT) = pi / 1024
__device__ __constant__ float kScale = (float)(M_PI / 1024.0);

typedef int   v4i __attribute__((ext_vector_type(4)));
typedef float v4f __attribute__((ext_vector_type(4)));

// ---------------------------------------------------------------------------
// Kernel A: convert x (f32, 376832) -> fp16 in d_ws, zero-padded to 393216
// halves so the staging loop can read a full 12*64KB without touching
// uninitialized bytes.
// ---------------------------------------------------------------------------
__global__ __launch_bounds__(256) void convert_x_kernel(
    const float* __restrict__ x, ushort* __restrict__ xh)
{
    const int t = blockIdx.x * 256 + threadIdx.x;   // 0..98303
    const int e = t * 4;
    ushort4 u;
    if (e < SINO_LEN) {                  // SINO_LEN % 4 == 0, so full quads
        const float4 v = *(const float4*)(x + e);
        u.x = __half_as_ushort(__float2half(v.x));
        u.y = __half_as_ushort(__float2half(v.y));
        u.z = __half_as_ushort(__float2half(v.z));
        u.w = __half_as_ushort(__float2half(v.w));
    } else {
        u.x = u.y = u.z = u.w = 0;
    }
    *(ushort4*)(xh + e) = u;
}

// ---------------------------------------------------------------------------
// Kernel B: segmented-LDS backprojection.
//
// Rationale (rounds 0-3 evidence): the global-gather formulation is bound by
// the per-CU cache-fill rate for random 4B loads (~0.36 fills/cyc/CU; sc0,
// nt, issue-order, occupancy all neutral). This formulation removes the
// TCP/L2 path from the gathers entirely: x (fp16, 736KB) is staged through
// LDS in 12 x 64KB segments; each thread holds 32 (index,weight) pairs in
// registers and resolves them against each resident segment with a
// predicated ds_read_u16 (out-of-window pairs read offset 0 with zeroed
// weight -> contribute nothing; every index falls in exactly one window).
//
// Geometry: 4096 blocks x 512 threads; block owns 16 voxels; 32 threads per
// voxel, 32 pairs per thread; 64KB dynamic LDS -> 2 blocks/CU resident, so
// one block's pairs-load/staging (VMEM) overlaps the sibling's LDS checks.
// ---------------------------------------------------------------------------
__global__ __launch_bounds__(512, 4) void backproj_lds_kernel(
    const ushort* __restrict__ xh,    // [XWS_HALVES] fp16 x, zero-padded
    const float*  __restrict__ weight,// [NVOX * PER_VOX]
    const float*  __restrict__ bias,  // [NVOX]
    const int*    __restrict__ indices,// [NVOX * PER_VOX]
    float*        __restrict__ out)   // [NVOX]
{
    extern __shared__ unsigned char xs[];  // 65536 B = one fp16 x segment

    const int tid  = threadIdx.x;       // 0..511
    const int lane = tid & 63;
    const int wid  = tid >> 6;          // wave id 0..7
    const int vv   = tid >> 5;          // voxel-in-block 0..15
    const int q    = tid & 31;          // thread-in-voxel 0..31

    const int    vox0  = blockIdx.x * 16;
    const size_t pbase = (size_t)(vox0 + vv) * PER_VOX;

    const v4i* ip = (const v4i*)(indices + pbase);
    const v4f* wp = (const v4f*)(weight + pbase);

    // Load my 32 pairs: 8 int4 + 8 float4, int4 #(q + 32k) of my voxel.
    // Consecutive q -> consecutive 16B -> coalesced. Non-temporal: these
    // streams must not evict xh from L2.
    v4i i4[8];
    v4f w4[8];
#pragma unroll
    for (int k = 0; k < 8; ++k) i4[k] = __builtin_nontemporal_load(&ip[q + k * 32]);
#pragma unroll
    for (int k = 0; k < 8; ++k) w4[k] = __builtin_nontemporal_load(&wp[q + k * 32]);
    // Convert element indices to byte offsets into fp16 x (idx*2).
#pragma unroll
    for (int k = 0; k < 8; ++k) {
        i4[k].x <<= 1; i4[k].y <<= 1; i4[k].z <<= 1; i4[k].w <<= 1;
    }

    // Per-thread staging slot: wave stages 8KB, call k moves 1KB
    // (64 lanes x 16B). LDS dest = uniform base + lane*16 (exact
    // global_load_lds pattern; linear layout, no swizzle).
    const unsigned sbase = (unsigned)(wid * 8192 + lane * 16);

    float s = 0.0f;

    for (int p = 0; p < NPASS; ++p) {
        const unsigned loB = (unsigned)p * SEGB;

        // Stage segment p: global (fp16 x) -> LDS, 16B per lane per call.
#pragma unroll
        for (int k = 0; k < 8; ++k) {
            const unsigned off = sbase + (unsigned)(k * 1024);
            __builtin_amdgcn_global_load_lds(
                (const __attribute__((address_space(1))) unsigned int*)
                    ((const unsigned char*)xh + loB + off),
                (__attribute__((address_space(3))) unsigned int*)(xs + off),
                16, 0, 0);
        }
        __syncthreads();   // drains vmcnt: staged bytes visible to all

        // Resolve my 32 pairs against this segment.
#pragma unroll
        for (int k = 0; k < 8; ++k) {
            {
                const unsigned off = (unsigned)i4[k].x - loB;   // wraps if below
                const bool in = off < (unsigned)SEGB;
                const unsigned a = in ? off : 0u;
                const float val = __half2float(*(const __half*)(xs + a));
                s = fmaf(val, in ? w4[k].x : 0.0f, s);
            }
            {
                const unsigned off = (unsigned)i4[k].y - loB;
                const bool in = off < (unsigned)SEGB;
                const unsigned a = in ? off : 0u;
                const float val = __half2float(*(const __half*)(xs + a));
                s = fmaf(val, in ? w4[k].y : 0.0f, s);
            }
            {
                const unsigned off = (unsigned)i4[k].z - loB;
                const bool in = off < (unsigned)SEGB;
                const unsigned a = in ? off : 0u;
                const float val = __half2float(*(const __half*)(xs + a));
                s = fmaf(val, in ? w4[k].z : 0.0f, s);
            }
            {
                const unsigned off = (unsigned)i4[k].w - loB;
                const bool in = off < (unsigned)SEGB;
                const unsigned a = in ? off : 0u;
                const float val = __half2float(*(const __half*)(xs + a));
                s = fmaf(val, in ? w4[k].w : 0.0f, s);
            }
        }
        __syncthreads();   // all reads done before next stage overwrites
    }

    // Reduce across the 32 threads of my voxel (within-wave, xor<32 stays
    // inside each 32-lane group).
#pragma unroll
    for (int off = 16; off > 0; off >>= 1)
        s += __shfl_xor(s, off, 64);

    if (q == 0) {
        const int v = vox0 + vv;
        out[NVOX - 1 - v] = bias[v] + kScale * s;   // flip both spatial axes
    }
}

// ---------------------------------------------------------------------------
// Fallback (round-3 kernel, proven 305 us/dispatch) if workspace is too
// small for the fp16 x copy.
// ---------------------------------------------------------------------------
__global__ __launch_bounds__(256) void backproj_fallback_kernel(
    const float* __restrict__ x,
    const float* __restrict__ weight,
    const float* __restrict__ bias,
    const int*   __restrict__ indices,
    float*       __restrict__ out)
{
    const int wave_in_block = threadIdx.x >> 6;
    const int lane          = threadIdx.x & 63;
    const int v             = blockIdx.x * 4 + wave_in_block;
    const size_t base       = (size_t)v * PER_VOX;

    const v4i* ip = (const v4i*)(indices + base);
    const v4f* wp = (const v4f*)(weight + base);

    v4i i4[4];
#pragma unroll
    for (int k = 0; k < 4; ++k)
        i4[k] = __builtin_nontemporal_load(&ip[lane + k * 64]);

    float g[16];
#pragma unroll
    for (int k = 0; k < 4; ++k) {
        g[4 * k + 0] = x[i4[k].x];
        g[4 * k + 1] = x[i4[k].y];
        g[4 * k + 2] = x[i4[k].z];
        g[4 * k + 3] = x[i4[k].w];
    }

    v4f w4[4];
#pragma unroll
    for (int k = 0; k < 4; ++k)
        w4[k] = __builtin_nontemporal_load(&wp[lane + k * 64]);

    float s = 0.0f;
#pragma unroll
    for (int k = 0; k < 4; ++k) {
        s += g[4 * k + 0] * w4[k].x;
        s += g[4 * k + 1] * w4[k].y;
        s += g[4 * k + 2] * w4[k].z;
        s += g[4 * k + 3] * w4[k].w;
    }

#pragma unroll
    for (int off = 32; off > 0; off >>= 1)
        s += __shfl_down(s, off, 64);

    if (lane == 0)
        out[NVOX - 1 - v] = bias[v] + kScale * s;
}

extern "C" void kernel_launch(void* const* d_in, const int* in_sizes, int n_in,
                              void* d_out, int out_size, void* d_ws, size_t ws_size,
                              hipStream_t stream) {
    const float* x       = (const float*)d_in[0];
    const float* weight  = (const float*)d_in[1];
    const float* bias    = (const float*)d_in[2];
    const int*   indices = (const int*)d_in[3];
    float*       out     = (float*)d_out;

    if (ws_size >= (size_t)XWS_BYTES) {
        ushort* xh = (ushort*)d_ws;
        // Kernel A: f32 -> fp16 (+ zero pad). 98304 quads / 256 = 384 blocks.
        convert_x_kernel<<<XWS_HALVES / 4 / 256, 256, 0, stream>>>(x, xh);
        // Kernel B: segmented-LDS backprojection.
        backproj_lds_kernel<<<NVOX / 16, 512, SEGB, stream>>>(
            xh, weight, bias, indices, out);
    } else {
        backproj_fallback_kernel<<<NVOX / 4, 256, 0, stream>>>(
            x, weight, bias, indices, out);
    }
}